// Round 11
// baseline (379.079 us; speedup 1.0000x reference)
//
#include <hip/hip_runtime.h>
#include <hip/hip_bf16.h>

#define EMB   1024
#define HEADS 16
#define HDIM  64
#define BB    4
#define SS    2048
#define MROWS (BB*SS)   // 8192

typedef __bf16 bf16_t;
typedef __bf16 bf16x4_t __attribute__((ext_vector_type(4)));
typedef __bf16 bf16x8   __attribute__((ext_vector_type(8)));
typedef float  f32x4    __attribute__((ext_vector_type(4)));

// async global->LDS, 16B/lane; LDS base wave-uniform, HW adds lane*16
__device__ __forceinline__ void glds16(const void* g, void* l) {
  __builtin_amdgcn_global_load_lds(
      (const __attribute__((address_space(1))) void*)g,
      (__attribute__((address_space(3))) void*)l, 16, 0, 0);
}

// ---------------------------------------------------------------------------
// Weights-only fp32->bf16 cast: grid (512,1,4), z = Wq,Wk,Wv,Wo (1M elems).
// Activation casts are fused into gemm_qkv's fp32 A-staging.
// ---------------------------------------------------------------------------
__launch_bounds__(256)
__global__ void cast_w(const float* s0, const float* s1, const float* s2,
                       const float* s3,
                       bf16_t* d0, bf16_t* d1, bf16_t* d2, bf16_t* d3) {
  const int z = blockIdx.z;
  const float* ss[4] = {s0, s1, s2, s3};
  bf16_t*      dd[4] = {d0, d1, d2, d3};
  const float* s = ss[z];
  bf16_t*      d = dd[z];
  const int i = (blockIdx.x*256 + threadIdx.x) * 8;
  const f32x4 a = *(const f32x4*)&s[i];
  const f32x4 b = *(const f32x4*)&s[i+4];
  bf16x8 r;
  r[0]=(bf16_t)a[0]; r[1]=(bf16_t)a[1]; r[2]=(bf16_t)a[2]; r[3]=(bf16_t)a[3];
  r[4]=(bf16_t)b[0]; r[5]=(bf16_t)b[1]; r[6]=(bf16_t)b[2]; r[7]=(bf16_t)b[3];
  *(bf16x8*)&d[i] = r;
}

// ---------------------------------------------------------------------------
// QKV projection GEMM, fp32 A with IDENTITY-MAPPED staging (the attn-K
// pattern, 3rd fusion attempt -- R4 failed on write conflicts, R6 on read
// conflicts from a bad XOR).  Each lane's glds16 global source IS the
// fragment it reads back: chunk c (16 x 1KB) = (row-group g=c>>1, half
// h=c&1); lane (quad,l16) sources A[(bm0+g*16+l16)*EMB + k0 + quad*8 + h*4]
// (16B fp32).  LDS write is HW-linear (lane*16B); fragment read is lane i ->
// slot i*16B: ZERO bank conflicts by construction.  cvt fp32->bf16 at
// fragment-read time -- bit-identical to cast-then-GEMM.  W stays bf16 via
// the proven 16-row chunk staging.  LDS 16KB(A f32)+8KB(W)=24KB, 1 barrier
// pair per K-step (m97 schedule).
// XCD swizzle: each (z,bm) A-panel owned by one XCD -> A fp32 read from HBM
// once (512KB panel L2-hot across 8 bn-iterations), W(z) 2MB hot.
//   z: 0 = Q (row-major out, sscale), 1 = K (row-major), 2 = V (packed V^T).
// ---------------------------------------------------------------------------
__launch_bounds__(256)
__global__ void gemm_qkv(const float* A0, const float* A1, const float* A2,
                         const bf16_t* W0, const bf16_t* W1, const bf16_t* W2,
                         bf16_t* C0, bf16_t* C1, bf16_t* C2, float sscale) {
  __shared__ __align__(16) float  Asf[16*256];  // 16 chunks x 64 lanes x 4 f32
  __shared__ __align__(16) bf16_t Bs[8*512];    // 8 chunks x 16 rows x 32 bf16
  const int tid  = threadIdx.x;
  const int wave = tid >> 6, lane = tid & 63;
  const int quad = lane >> 4, l16 = lane & 15;
  const int wm = wave >> 1, wn = wave & 1;

  // XCD swizzle: fid -> (z, bm, bn)
  const int fid = blockIdx.x + 8*(blockIdx.y + 64*blockIdx.z);
  const int xcd = fid & 7, s = fid >> 3;
  const int bn0 = (s & 7) * 128;
  const int p   = xcd + 8*(s >> 3);            // (z,bm) pair, unique per XCD
  const int z   = p >> 6;
  const int bm0 = (p & 63) * 128;

  const float*  A = (z == 0) ? A0 : (z == 1) ? A1 : A2;
  const bf16_t* W = (z == 0) ? W0 : (z == 1) ? W1 : W2;
  bf16_t*       C = (z == 0) ? C0 : (z == 1) ? C1 : C2;
  const float oscale = (z == 0) ? sscale : 1.0f;

  f32x4 acc[4][4] = {};

  for (int k0 = 0; k0 < EMB; k0 += 32) {
    // stage A fp32, identity-mapped: 16 chunks, 4 per wave
#pragma unroll
    for (int cc = 0; cc < 4; ++cc) {
      const int c = wave*4 + cc;               // chunk 0..15
      const int g = c >> 1, h = c & 1;
      glds16(A + (size_t)(bm0 + g*16 + l16)*EMB + k0 + quad*8 + h*4,
             &Asf[c*256]);
    }
    // stage W bf16: 8 chunks of 16 rows x 32 bf16; 2 per wave
#pragma unroll
    for (int j = 0; j < 2; ++j) {
      const int i   = wave*2 + j;              // chunk 0..7
      const int row = i*16 + (lane >> 2);
      const int col = (lane & 3) * 8;
      glds16(W + (size_t)(bn0 + row)*EMB + k0 + col, &Bs[i*512]);
    }
    __syncthreads();

    bf16x8 a[4], b[4];
#pragma unroll
    for (int t2 = 0; t2 < 4; ++t2) {
      const int g = wm*4 + t2;                 // this wave's row-group
      const f32x4 v0 = *(const f32x4*)&Asf[(g*2    )*256 + lane*4];
      const f32x4 v1 = *(const f32x4*)&Asf[(g*2 + 1)*256 + lane*4];
#pragma unroll
      for (int r = 0; r < 4; ++r) {
        a[t2][r]     = (bf16_t)v0[r];
        a[t2][4 + r] = (bf16_t)v1[r];
      }
      b[t2] = *(const bf16x8*)&Bs[(wn*64 + t2*16 + l16)*32 + quad*8];
    }
#pragma unroll
    for (int mt = 0; mt < 4; ++mt)
#pragma unroll
      for (int nt = 0; nt < 4; ++nt)
        acc[mt][nt] = __builtin_amdgcn_mfma_f32_16x16x32_bf16(a[mt], b[nt], acc[mt][nt], 0, 0, 0);
    __syncthreads();
  }

  if (z == 2) {
    // packed-V^T epilogue: acc[mt][nt][r] = V[s=bm0+wm*64+mt*16+quad*4+r][d]
    // chunk(ks,nt) = {acc[2ks][nt][0..3], acc[2ks+1][nt][0..3]}
    const int bb = bm0 >> 11;                    // batch (2048 rows each)
    const int T  = ((bm0 & 2047) >> 6) + wm;     // 64-key tile within batch
    const int h  = (bn0 >> 6) + wn;              // head (64 cols each)
    bf16_t* base = C + ((size_t)(bb*HEADS + h)*32 + T)*4096;
#pragma unroll
    for (int ks = 0; ks < 2; ++ks)
#pragma unroll
      for (int nt = 0; nt < 4; ++nt) {
        bf16x8 v;
#pragma unroll
        for (int r = 0; r < 4; ++r) {
          v[r]     = (bf16_t)acc[2*ks][nt][r];
          v[4 + r] = (bf16_t)acc[2*ks + 1][nt][r];
        }
        *(bf16x8*)&base[((nt*2 + ks)*64 + quad*16 + l16)*8] = v;
      }
  } else {
    // row-major epilogue: C/D layout col=l16, row=quad*4+reg
#pragma unroll
    for (int mt = 0; mt < 4; ++mt) {
      const int row = bm0 + wm*64 + mt*16 + quad*4;
#pragma unroll
      for (int nt = 0; nt < 4; ++nt) {
        const int col = bn0 + wn*64 + nt*16 + l16;
#pragma unroll
        for (int r = 0; r < 4; ++r)
          C[(size_t)(row + r)*EMB + col] = (bf16_t)(acc[mt][nt][r] * oscale);
      }
    }
  }
}

// ---------------------------------------------------------------------------
// Output GEMM: fp32 C, row-major.  64x128 tile, single-buffered (R10-proven:
// 312.6us total, -9us vs 128x128).  1024 blocks -> 4 blocks/CU, 16 waves/CU.
// acc[2][4], LDS 12KB.  XCD swizzle: each XCD owns 16 consecutive 64-row
// bm-panels (A L2-hot, bn time-local, W 2MB hot).
// ---------------------------------------------------------------------------
__launch_bounds__(256)
__global__ void gemm_out(const bf16_t* __restrict__ A, const bf16_t* __restrict__ W,
                         float* __restrict__ C) {
  __shared__ __align__(16) bf16_t As[64*32];     // 4KB
  __shared__ __align__(16) bf16_t Bs[128*32];    // 8KB
  const int tid  = threadIdx.x;
  const int wave = tid >> 6, lane = tid & 63;
  const int quad = lane >> 4, l16 = lane & 15;
  const int wm = wave >> 1, wn = wave & 1;       // wave: 32 rows x 64 cols

  // grid (8,128): fid -> xcd 0..7, s 0..127
  const int fid = blockIdx.x + 8*blockIdx.y;
  const int xcd = fid & 7, s = fid >> 3;
  const int bn0 = (s & 7) * 128;
  const int bm0 = (xcd*16 + (s >> 3)) * 64;      // 16 bm-panels per XCD

  f32x4 acc[2][4] = {};

  for (int k0 = 0; k0 < EMB; k0 += 32) {
    {
      const int i   = wave;                      // A chunk 0..3
      const int row = i*16 + (lane >> 2);
      const int col = (lane & 3) * 8;
      glds16(A + (size_t)(bm0 + row)*EMB + k0 + col, &As[i*512]);
    }
#pragma unroll
    for (int j = 0; j < 2; ++j) {
      const int i   = wave*2 + j;                // B chunk 0..7
      const int row = i*16 + (lane >> 2);
      const int col = (lane & 3) * 8;
      glds16(W + (size_t)(bn0 + row)*EMB + k0 + col, &Bs[i*512]);
    }
    __syncthreads();

    bf16x8 a[2], b[4];
#pragma unroll
    for (int t2 = 0; t2 < 2; ++t2)
      a[t2] = *(const bf16x8*)&As[(wm*32 + t2*16 + l16)*32 + quad*8];
#pragma unroll
    for (int t2 = 0; t2 < 4; ++t2)
      b[t2] = *(const bf16x8*)&Bs[(wn*64 + t2*16 + l16)*32 + quad*8];
#pragma unroll
    for (int mt = 0; mt < 2; ++mt)
#pragma unroll
      for (int nt = 0; nt < 4; ++nt)
        acc[mt][nt] = __builtin_amdgcn_mfma_f32_16x16x32_bf16(a[mt], b[nt], acc[mt][nt], 0, 0, 0);
    __syncthreads();
  }

#pragma unroll
  for (int mt = 0; mt < 2; ++mt) {
    const int row = bm0 + wm*32 + mt*16 + quad*4;
#pragma unroll
    for (int nt = 0; nt < 4; ++nt) {
      const int col = bn0 + wn*64 + nt*16 + l16;
#pragma unroll
      for (int r = 0; r < 4; ++r)
        C[(size_t)(row + r)*EMB + col] = acc[mt][nt][r];
    }
  }
}

// ---------------------------------------------------------------------------
// Flash attention, Q-tile 128, 8 waves x 16 q-rows (512 threads), K-tile 64.
// S^T = MFMA(A=K, B=Q) gives the P^T B-operand layout directly (regs = 4
// keys, lane l16 = qrow); packed V^T from the V-GEMM epilogue is the
// A-operand of O^T = V^T P^T with zero data movement.  No-max softmax (scale
// folded into Q projection), raw v_exp_f32, deferred l-reduction.
// 8 waves + <=64-reg bracket -> 32 waves/CU (R3: occupancy 63%, 86us).
// 2-phase dbuf: stage t+1 right after the single per-tile barrier; vmcnt(0)
// drain at next barrier lands after a full tile of compute.
// K staged directly in MFMA A-fragment order via per-lane global src (lane
// i -> slot i: bank-conflict-free); packed V^T is an identity copy.
// XCD swizzle: all 16 q-blocks of one (b,h) land consecutively on one XCD.
// Qp and Cx alias (disjoint per-block slices, read-before-write).
// ---------------------------------------------------------------------------
__launch_bounds__(512, 8)
__global__ void attn(const bf16_t* Qp, const bf16_t* __restrict__ Kp,
                     const bf16_t* __restrict__ Vt, bf16_t* Cx) {
  __shared__ __align__(16) bf16_t Ks[2][4096];  // [buf][chunk][lane*8]  16KB
  __shared__ __align__(16) bf16_t Vs[2][4096];  // [buf][packed V^T]     16KB

  const int tid  = threadIdx.x;
  const int wave = tid >> 6, lane = tid & 63;
  const int quad = lane >> 4, l16 = lane & 15;

  // XCD swizzle: fid -> (b, h, q-block); gridDim = (16, 16, 4)
  const int fid  = blockIdx.x + 16*(blockIdx.y + 16*blockIdx.z);
  const int xcd  = fid & 7, s = fid >> 3;
  const int q0   = (s & 15) * 128;
  const int pair = xcd*8 + (s >> 4);    // 0..63, unique per XCD
  const int h    = pair & 15;
  const int b    = pair >> 4;

  // Q fragments (B-operand of S^T): lane l16 = qrow, k = d = quad*8+j (+32ks)
  bf16x8 qf[2];
  {
    const size_t qr = (size_t)(b*SS + q0 + wave*16 + l16)*EMB + h*HDIM;
    qf[0] = *(const bf16x8*)&Qp[qr + quad*8];
    qf[1] = *(const bf16x8*)&Qp[qr + 32 + quad*8];
  }

  const bf16_t* Kb = Kp + (size_t)b*SS*EMB + h*HDIM;
  const bf16_t* Vb = Vt + ((size_t)(b*HEADS + h)*32)*4096;

  f32x4 o[4] = {};             // O^T: lane l16 = qrow, row = d = quad*4+r
  f32x4 lsv = {};              // packed denominator accumulator

  // stage K/V tile ti into buffer bf: 1 K-chunk + 1 V-chunk per wave.
  auto stage = [&](int ti, int bf) {
    const int t0 = ti * 64;
    const int i  = wave;                 // chunk 0..7
    glds16(Kb + (size_t)(t0 + (i&3)*16 + l16)*EMB + (i>>2)*32 + quad*8,
           &Ks[bf][i*512]);
    glds16(Vb + (size_t)ti*4096 + i*512 + lane*8, &Vs[bf][i*512]);
  };

  stage(0, 0);

  const int NT = SS / 64;      // 32 tiles
  for (int t = 0, buf = 0; t < NT; ++t, buf ^= 1) {
    // barrier: (a) vmcnt(0) drain completes stage(t,buf) -- which has had a
    // full tile of compute to finish; (b) all waves done reading buf^1.
    __syncthreads();
    if (t + 1 < NT) stage(t + 1, buf ^ 1);

    // S^T = K Q^T : A = K-frag (lane l16 = key), B = Q-frag  (8 MFMA)
    f32x4 st[4] = {};
#pragma unroll
    for (int cb = 0; cb < 4; ++cb) {
      const bf16x8 kf0 = *(const bf16x8*)&Ks[buf][cb*512 + lane*8];
      const bf16x8 kf1 = *(const bf16x8*)&Ks[buf][2048 + cb*512 + lane*8];
      st[cb] = __builtin_amdgcn_mfma_f32_16x16x32_bf16(kf0, qf[0], st[cb], 0, 0, 0);
      st[cb] = __builtin_amdgcn_mfma_f32_16x16x32_bf16(kf1, qf[1], st[cb], 0, 0, 0);
    }

    // softmax (no-max): p = exp2(s); pack P^T B-fragments directly from regs
#pragma unroll
    for (int kb = 0; kb < 4; ++kb) {
#pragma unroll
      for (int r = 0; r < 4; ++r)
        st[kb][r] = __builtin_amdgcn_exp2f(st[kb][r]);
      lsv += st[kb];           // packed v_pk_add_f32
    }
    bf16x8 pb[2];
#pragma unroll
    for (int ks = 0; ks < 2; ++ks)
#pragma unroll
      for (int r = 0; r < 4; ++r) {
        pb[ks][r]     = (bf16_t)st[2*ks][r];
        pb[ks][4 + r] = (bf16_t)st[2*ks + 1][r];
      }

    // O^T += V^T P^T : A = packed V^T chunk, B = pb  (8 MFMA)
#pragma unroll
    for (int ks = 0; ks < 2; ++ks)
#pragma unroll
      for (int dt = 0; dt < 4; ++dt) {
        const bf16x8 vf = *(const bf16x8*)&Vs[buf][((dt*2 + ks)*64 + lane)*8];
        o[dt] = __builtin_amdgcn_mfma_f32_16x16x32_bf16(vf, pb[ks], o[dt], 0, 0, 0);
      }
  }

  // l-reduce across quads (lanes sharing l16) + write O^T as [row][h*64+d]
  float l = lsv[0] + lsv[1] + lsv[2] + lsv[3];
  l += __shfl_xor(l, 16, 64);
  l += __shfl_xor(l, 32, 64);
  const float inv = 1.0f / l;
  const size_t row = (size_t)(b*SS + q0 + wave*16 + l16)*EMB + h*HDIM;
#pragma unroll
  for (int dt = 0; dt < 4; ++dt) {
    bf16x4_t v;
#pragma unroll
    for (int r = 0; r < 4; ++r) v[r] = (bf16_t)(o[dt][r] * inv);
    *(bf16x4_t*)&Cx[row + dt*16 + quad*4] = v;
  }
}

// ---------------------------------------------------------------------------
extern "C" void kernel_launch(void* const* d_in, const int* in_sizes, int n_in,
                              void* d_out, int out_size, void* d_ws, size_t ws_size,
                              hipStream_t stream) {
  (void)in_sizes; (void)n_in; (void)out_size; (void)ws_size;
  const float* query = (const float*)d_in[0];
  const float* key   = (const float*)d_in[1];
  const float* value = (const float*)d_in[2];
  const float* WqF   = (const float*)d_in[3];
  const float* WkF   = (const float*)d_in[4];
  const float* WvF   = (const float*)d_in[5];
  const float* WoF   = (const float*)d_in[6];

  const size_t AN = (size_t)MROWS*EMB;   // 8M elems
  const size_t WN = (size_t)EMB*EMB;     // 1M elems
  float* out = (float*)d_out;
  bf16_t* S5 = (bf16_t*)d_out;           // d_out first 16MB: packed V^T
  bf16_t* S6 = S5 + AN;                  // d_out second 16MB: K projection

  // ws layout (24MB, proven R4/R6): S2 (Q proj / attn ctx) | Wq|Wk|Wv|Wo
  bf16_t* S2  = (bf16_t*)d_ws;
  bf16_t* Wqb = S2 + AN;
  bf16_t* Wkb = Wqb + WN;
  bf16_t* Wvb = Wkb + WN;
  bf16_t* Wob = Wvb + WN;

  const float sscale = 0.125f * 1.44269504f;  // 1/sqrt(64)*log2(e) into Q

  const dim3 gw  (512, 1, 4);
  const dim3 gqkv(EMB/128, MROWS/128, 3);
  const dim3 gg  (8, 128);               // 64x128 tiles: 1024 blocks
  const dim3 gattn(SS/128, HEADS, BB);

  cast_w<<<gw, 256, 0, stream>>>(WqF, WkF, WvF, WoF, Wqb, Wkb, Wvb, Wob);
  gemm_qkv<<<gqkv, 256, 0, stream>>>(query, key, value, Wqb, Wkb, Wvb,
                                     S2, S6, S5, sscale);
  attn<<<gattn, 512, 0, stream>>>(S2, S6, S5, S2);
  gemm_out<<<gg, 256, 0, stream>>>(S2, Wob, out);
}

// Round 12
// 324.015 us; speedup vs baseline: 1.1699x; 1.1699x over previous
//
#include <hip/hip_runtime.h>
#include <hip/hip_bf16.h>

#define EMB   1024
#define HEADS 16
#define HDIM  64
#define BB    4
#define SS    2048
#define MROWS (BB*SS)   // 8192

typedef __bf16 bf16_t;
typedef __bf16 bf16x4_t __attribute__((ext_vector_type(4)));
typedef __bf16 bf16x8   __attribute__((ext_vector_type(8)));
typedef float  f32x4    __attribute__((ext_vector_type(4)));

// async global->LDS, 16B/lane; LDS base wave-uniform, HW adds lane*16
__device__ __forceinline__ void glds16(const void* g, void* l) {
  __builtin_amdgcn_global_load_lds(
      (const __attribute__((address_space(1))) void*)g,
      (__attribute__((address_space(3))) void*)l, 16, 0, 0);
}

// ---------------------------------------------------------------------------
// Multi-tensor fp32->bf16 cast. z < nact: 8M-elem activations (4096 blocks);
// z >= nact: 1M-elem weights (first 512 blocks active).
// ---------------------------------------------------------------------------
__launch_bounds__(256)
__global__ void cast_multi(const float* s0, const float* s1, const float* s2,
                           const float* s3, const float* s4, const float* s5,
                           const float* s6,
                           bf16_t* d0, bf16_t* d1, bf16_t* d2, bf16_t* d3,
                           bf16_t* d4, bf16_t* d5, bf16_t* d6, int nact) {
  const int z = blockIdx.z;
  if (z >= nact && blockIdx.x >= 512) return;
  const float* ss[7] = {s0, s1, s2, s3, s4, s5, s6};
  bf16_t*      dd[7] = {d0, d1, d2, d3, d4, d5, d6};
  const float* s = ss[z];
  bf16_t*      d = dd[z];
  const int i = (blockIdx.x*256 + threadIdx.x) * 8;
  const f32x4 a = *(const f32x4*)&s[i];
  const f32x4 b = *(const f32x4*)&s[i+4];
  bf16x8 r;
  r[0]=(bf16_t)a[0]; r[1]=(bf16_t)a[1]; r[2]=(bf16_t)a[2]; r[3]=(bf16_t)a[3];
  r[4]=(bf16_t)b[0]; r[5]=(bf16_t)b[1]; r[6]=(bf16_t)b[2]; r[7]=(bf16_t)b[3];
  *(bf16x8*)&d[i] = r;
}

__launch_bounds__(256)
__global__ void cast_f32_bf16(const float* __restrict__ src, bf16_t* __restrict__ dst) {
  const int i = (blockIdx.x*256 + threadIdx.x) * 8;
  const f32x4 a = *(const f32x4*)&src[i];
  const f32x4 b = *(const f32x4*)&src[i+4];
  bf16x8 r;
  r[0]=(bf16_t)a[0]; r[1]=(bf16_t)a[1]; r[2]=(bf16_t)a[2]; r[3]=(bf16_t)a[3];
  r[4]=(bf16_t)b[0]; r[5]=(bf16_t)b[1]; r[6]=(bf16_t)b[2]; r[7]=(bf16_t)b[3];
  *(bf16x8*)&dst[i] = r;
}

// ---------------------------------------------------------------------------
// Shared GEMM core: acc[4][4] += A_tile @ W_tile^T over full K=EMB.
// 128x128 tile, BK=32, glds16 staging, 16 MFMA/K-step (m97 structure,
// single-buffered -- the R1-proven form).
// ---------------------------------------------------------------------------
__device__ __forceinline__ void gemm_core(const bf16_t* __restrict__ A,
                                          const bf16_t* __restrict__ W,
                                          bf16_t* As, bf16_t* Bs,
                                          f32x4 acc[4][4],
                                          int bm0, int bn0,
                                          int wave, int lane) {
  const int quad = lane >> 4, l16 = lane & 15;
  const int wm = wave >> 1, wn = wave & 1;
  for (int k0 = 0; k0 < EMB; k0 += 32) {
#pragma unroll
    for (int j = 0; j < 2; ++j) {
      const int i   = wave*2 + j;              // chunk 0..7 (512 bf16 = 1KB)
      const int row = i*16 + (lane >> 2);
      const int col = (lane & 3) * 8;
      glds16(A + (size_t)(bm0 + row)*EMB + k0 + col, &As[i*512]);
      glds16(W + (size_t)(bn0 + row)*EMB + k0 + col, &Bs[i*512]);
    }
    __syncthreads();

    bf16x8 a[4], b[4];
#pragma unroll
    for (int t = 0; t < 4; ++t) {
      a[t] = *(const bf16x8*)&As[(wm*64 + t*16 + l16)*32 + quad*8];
      b[t] = *(const bf16x8*)&Bs[(wn*64 + t*16 + l16)*32 + quad*8];
    }
#pragma unroll
    for (int mt = 0; mt < 4; ++mt)
#pragma unroll
      for (int nt = 0; nt < 4; ++nt)
        acc[mt][nt] = __builtin_amdgcn_mfma_f32_16x16x32_bf16(a[mt], b[nt], acc[mt][nt], 0, 0, 0);
    __syncthreads();
  }
}

// ---------------------------------------------------------------------------
// Fused projection GEMM with XCD-aware swizzle.  Flat block id fid is
// round-robined over 8 XCDs by HW; we remap so each (z,bm) A-panel is owned
// by exactly one XCD (read once from HBM) with bn iterating time-locally,
// and W(z) (2MB) staying hot in that XCD's 4MB L2.
//   z (+zbase): 0 = Q (row-major, sscale), 1 = K (row-major), 2 = V (packed).
// ---------------------------------------------------------------------------
__launch_bounds__(256)
__global__ void gemm_qkv(const bf16_t* A0, const bf16_t* A1, const bf16_t* A2,
                         const bf16_t* W0, const bf16_t* W1, const bf16_t* W2,
                         bf16_t* C0, bf16_t* C1, bf16_t* C2,
                         float sscale, int zbase) {
  __shared__ __align__(16) bf16_t As[128*32];
  __shared__ __align__(16) bf16_t Bs[128*32];
  const int tid  = threadIdx.x;
  const int wave = tid >> 6, lane = tid & 63;
  const int quad = lane >> 4, l16 = lane & 15;
  const int wm = wave >> 1, wn = wave & 1;

  // XCD swizzle: fid -> (z, bm, bn)
  const int fid = blockIdx.x + 8*(blockIdx.y + 64*blockIdx.z);
  const int xcd = fid & 7, s = fid >> 3;
  const int bn0 = (s & 7) * 128;
  const int p   = xcd + 8*(s >> 3);            // (z,bm) pair, unique per XCD
  const int z   = (p >> 6) + zbase;
  const int bm0 = (p & 63) * 128;

  const bf16_t* A = (z == 0) ? A0 : (z == 1) ? A1 : A2;
  const bf16_t* W = (z == 0) ? W0 : (z == 1) ? W1 : W2;
  bf16_t*       C = (z == 0) ? C0 : (z == 1) ? C1 : C2;
  const float oscale = (z == 0) ? sscale : 1.0f;

  f32x4 acc[4][4] = {};
  gemm_core(A, W, As, Bs, acc, bm0, bn0, wave, lane);

  if (z == 2) {
    // packed-V^T epilogue: acc[mt][nt][r] = V[s=bm0+wm*64+mt*16+quad*4+r][d]
    // chunk(ks,nt) = {acc[2ks][nt][0..3], acc[2ks+1][nt][0..3]}
    const int bb = bm0 >> 11;                    // batch (2048 rows each)
    const int T  = ((bm0 & 2047) >> 6) + wm;     // 64-key tile within batch
    const int h  = (bn0 >> 6) + wn;              // head (64 cols each)
    bf16_t* base = C + ((size_t)(bb*HEADS + h)*32 + T)*4096;
#pragma unroll
    for (int ks = 0; ks < 2; ++ks)
#pragma unroll
      for (int nt = 0; nt < 4; ++nt) {
        bf16x8 v;
#pragma unroll
        for (int r = 0; r < 4; ++r) {
          v[r]     = (bf16_t)acc[2*ks][nt][r];
          v[4 + r] = (bf16_t)acc[2*ks + 1][nt][r];
        }
        *(bf16x8*)&base[((nt*2 + ks)*64 + quad*16 + l16)*8] = v;
      }
  } else {
    // row-major epilogue: C/D layout col=l16, row=quad*4+reg
#pragma unroll
    for (int mt = 0; mt < 4; ++mt) {
      const int row = bm0 + wm*64 + mt*16 + quad*4;
#pragma unroll
      for (int nt = 0; nt < 4; ++nt) {
        const int col = bn0 + wn*64 + nt*16 + l16;
#pragma unroll
        for (int r = 0; r < 4; ++r)
          C[(size_t)(row + r)*EMB + col] = (bf16_t)(acc[mt][nt][r] * oscale);
      }
    }
  }
}

// ---------------------------------------------------------------------------
// Output GEMM: fp32 C, row-major.  64x128 tile, single-buffered (R10-proven:
// 312.6us total, -9us vs 128x128).  1024 blocks -> 4 blocks/CU, 16 waves/CU.
// acc[2][4], LDS 12KB.  XCD swizzle: each XCD owns 16 consecutive 64-row
// bm-panels (A L2-hot, bn time-local, W 2MB hot).
// ---------------------------------------------------------------------------
__launch_bounds__(256)
__global__ void gemm_out(const bf16_t* __restrict__ A, const bf16_t* __restrict__ W,
                         float* __restrict__ C) {
  __shared__ __align__(16) bf16_t As[64*32];     // 4KB
  __shared__ __align__(16) bf16_t Bs[128*32];    // 8KB
  const int tid  = threadIdx.x;
  const int wave = tid >> 6, lane = tid & 63;
  const int quad = lane >> 4, l16 = lane & 15;
  const int wm = wave >> 1, wn = wave & 1;       // wave: 32 rows x 64 cols

  // grid (8,128): fid -> xcd 0..7, s 0..127
  const int fid = blockIdx.x + 8*blockIdx.y;
  const int xcd = fid & 7, s = fid >> 3;
  const int bn0 = (s & 7) * 128;
  const int bm0 = (xcd*16 + (s >> 3)) * 64;      // 16 bm-panels per XCD

  f32x4 acc[2][4] = {};

  for (int k0 = 0; k0 < EMB; k0 += 32) {
    {
      const int i   = wave;                      // A chunk 0..3
      const int row = i*16 + (lane >> 2);
      const int col = (lane & 3) * 8;
      glds16(A + (size_t)(bm0 + row)*EMB + k0 + col, &As[i*512]);
    }
#pragma unroll
    for (int j = 0; j < 2; ++j) {
      const int i   = wave*2 + j;                // B chunk 0..7
      const int row = i*16 + (lane >> 2);
      const int col = (lane & 3) * 8;
      glds16(W + (size_t)(bn0 + row)*EMB + k0 + col, &Bs[i*512]);
    }
    __syncthreads();

    bf16x8 a[2], b[4];
#pragma unroll
    for (int t2 = 0; t2 < 2; ++t2)
      a[t2] = *(const bf16x8*)&As[(wm*32 + t2*16 + l16)*32 + quad*8];
#pragma unroll
    for (int t2 = 0; t2 < 4; ++t2)
      b[t2] = *(const bf16x8*)&Bs[(wn*64 + t2*16 + l16)*32 + quad*8];
#pragma unroll
    for (int mt = 0; mt < 2; ++mt)
#pragma unroll
      for (int nt = 0; nt < 4; ++nt)
        acc[mt][nt] = __builtin_amdgcn_mfma_f32_16x16x32_bf16(a[mt], b[nt], acc[mt][nt], 0, 0, 0);
    __syncthreads();
  }

#pragma unroll
  for (int mt = 0; mt < 2; ++mt) {
    const int row = bm0 + wm*32 + mt*16 + quad*4;
#pragma unroll
    for (int nt = 0; nt < 4; ++nt) {
      const int col = bn0 + wn*64 + nt*16 + l16;
#pragma unroll
      for (int r = 0; r < 4; ++r)
        C[(size_t)(row + r)*EMB + col] = acc[mt][nt][r];
    }
  }
}

// ---------------------------------------------------------------------------
// Flash attention, Q-tile 128, 8 waves x 16 q-rows (512 threads), K-tile 64.
// S^T = MFMA(A=K, B=Q) gives the P^T B-operand layout directly (regs = 4
// keys, lane l16 = qrow); packed V^T from the V-GEMM epilogue is the
// A-operand of O^T = V^T P^T with zero data movement.  No-max softmax (scale
// folded into Q projection), raw v_exp_f32, deferred l-reduction.
//
// R12: one-tile SOFTWARE PIPELINE at the 8-wave config (retry of R2, whose
// regression was occupancy-blocked: 4-wave config VGPR 64->84.  Here the
// extra live state stn[4]+pb[2] fits the <=64-reg bracket, keeping 8
// waves/SIMD).  pb(t) is held across the barrier so QK(t+1) and PV(t) --
// fully independent -- issue as one 16-MFMA setprio-wrapped cluster;
// exp/pack(t+1) runs after bar2, overlapping the stage(t+2) drain.
//   buf: tile x lives in buf x&1.
//   iter t: bar1 (drains stage t+1) -> [QK(t+1) from Ks[buf^1] + PV(t) from
//   Vs[buf]] -> bar2 (all reads done) -> stage(t+2 -> buf) -> SM(t+1).
// K staged in MFMA A-frag order via per-lane global src (lane i -> slot i,
// conflict-free); packed V^T is an identity copy.
// XCD swizzle: all 16 q-blocks of one (b,h) land consecutively on one XCD.
// Qp and Cx alias (disjoint per-block slices, read-before-write).
// ---------------------------------------------------------------------------
__launch_bounds__(512, 8)
__global__ void attn(const bf16_t* Qp, const bf16_t* __restrict__ Kp,
                     const bf16_t* __restrict__ Vt, bf16_t* Cx) {
  __shared__ __align__(16) bf16_t Ks[2][4096];  // [buf][chunk][lane*8]  16KB
  __shared__ __align__(16) bf16_t Vs[2][4096];  // [buf][packed V^T]     16KB

  const int tid  = threadIdx.x;
  const int wave = tid >> 6, lane = tid & 63;
  const int quad = lane >> 4, l16 = lane & 15;

  // XCD swizzle: fid -> (b, h, q-block); gridDim = (16, 16, 4)
  const int fid  = blockIdx.x + 16*(blockIdx.y + 16*blockIdx.z);
  const int xcd  = fid & 7, s = fid >> 3;
  const int q0   = (s & 15) * 128;
  const int pair = xcd*8 + (s >> 4);    // 0..63, unique per XCD
  const int h    = pair & 15;
  const int b    = pair >> 4;

  // Q fragments (B-operand of S^T): lane l16 = qrow, k = d = quad*8+j (+32ks)
  bf16x8 qf[2];
  {
    const size_t qr = (size_t)(b*SS + q0 + wave*16 + l16)*EMB + h*HDIM;
    qf[0] = *(const bf16x8*)&Qp[qr + quad*8];
    qf[1] = *(const bf16x8*)&Qp[qr + 32 + quad*8];
  }

  const bf16_t* Kb = Kp + (size_t)b*SS*EMB + h*HDIM;
  const bf16_t* Vb = Vt + ((size_t)(b*HEADS + h)*32)*4096;

  f32x4 o[4] = {};             // O^T: lane l16 = qrow, row = d = quad*4+r
  f32x4 lsv = {};              // packed denominator accumulator
  bf16x8 pb[2];                // packed P^T B-fragments (pipeline register)

  // stage K/V tile ti into buffer bf: 1 K-chunk + 1 V-chunk per wave.
  auto stage = [&](int ti, int bf) {
    const int t0 = ti * 64;
    const int i  = wave;                 // chunk 0..7
    glds16(Kb + (size_t)(t0 + (i&3)*16 + l16)*EMB + (i>>2)*32 + quad*8,
           &Ks[bf][i*512]);
    glds16(Vb + (size_t)ti*4096 + i*512 + lane*8, &Vs[bf][i*512]);
  };

  // S^T = K Q^T : A = K-frag (lane l16 = key), B = Q-frag  (8 MFMA)
  auto QK = [&](int bf, f32x4 (&st)[4]) {
#pragma unroll
    for (int cb = 0; cb < 4; ++cb) {
      const bf16x8 kf0 = *(const bf16x8*)&Ks[bf][cb*512 + lane*8];
      const bf16x8 kf1 = *(const bf16x8*)&Ks[bf][2048 + cb*512 + lane*8];
      st[cb] = __builtin_amdgcn_mfma_f32_16x16x32_bf16(kf0, qf[0], st[cb], 0, 0, 0);
      st[cb] = __builtin_amdgcn_mfma_f32_16x16x32_bf16(kf1, qf[1], st[cb], 0, 0, 0);
    }
  };

  // softmax (no-max): p = exp2(s); pack P^T B-fragments directly from regs
  auto SM = [&](f32x4 (&st)[4]) {
#pragma unroll
    for (int kb = 0; kb < 4; ++kb) {
#pragma unroll
      for (int r = 0; r < 4; ++r)
        st[kb][r] = __builtin_amdgcn_exp2f(st[kb][r]);
      lsv += st[kb];           // packed v_pk_add_f32
    }
#pragma unroll
    for (int ks = 0; ks < 2; ++ks)
#pragma unroll
      for (int r = 0; r < 4; ++r) {
        pb[ks][r]     = (bf16_t)st[2*ks][r];
        pb[ks][4 + r] = (bf16_t)st[2*ks + 1][r];
      }
  };

  // O^T += V^T P^T : A = packed V^T chunk, B = pb  (8 MFMA)
  auto PV = [&](int bf) {
#pragma unroll
    for (int ks = 0; ks < 2; ++ks)
#pragma unroll
      for (int dt = 0; dt < 4; ++dt) {
        const bf16x8 vf = *(const bf16x8*)&Vs[bf][((dt*2 + ks)*64 + lane)*8];
        o[dt] = __builtin_amdgcn_mfma_f32_16x16x32_bf16(vf, pb[ks], o[dt], 0, 0, 0);
      }
  };

  // ---- prologue: tile 0 computed to P; tile 1 staged in flight -----------
  stage(0, 0);
  __syncthreads();             // drains stage(0)
  stage(1, 1);
  {
    f32x4 st[4] = {};
    QK(0, st);
    SM(st);                    // pb = P(0)
  }

  // ---- main pipeline: iter t finishes tile t, preps tile t+1 -------------
  const int NT = SS / 64;      // 32 tiles
  for (int t = 0; t < NT - 1; ++t) {
    const int buf = t & 1;
    __syncthreads();           // bar1: drains stage(t+1 -> buf^1)
    __builtin_amdgcn_s_setprio(1);
    f32x4 stn[4] = {};
    QK(buf ^ 1, stn);          // QK(t+1)  -- independent of PV(t)
    PV(buf);                   // PV(t)    -- consumes pb(t), Vs[buf]
    __builtin_amdgcn_s_setprio(0);
    __syncthreads();           // bar2: all reads of both bufs complete
    if (t + 2 < NT) stage(t + 2, buf);
    SM(stn);                   // pb = P(t+1); stage drains at next bar1
  }

  // ---- epilogue: PV(NT-1) from Vs[(NT-1)&1] ------------------------------
  PV((NT - 1) & 1);

  // l-reduce across quads (lanes sharing l16) + write O^T as [row][h*64+d]
  float l = lsv[0] + lsv[1] + lsv[2] + lsv[3];
  l += __shfl_xor(l, 16, 64);
  l += __shfl_xor(l, 32, 64);
  const float inv = 1.0f / l;
  const size_t row = (size_t)(b*SS + q0 + wave*16 + l16)*EMB + h*HDIM;
#pragma unroll
  for (int dt = 0; dt < 4; ++dt) {
    bf16x4_t v;
#pragma unroll
    for (int r = 0; r < 4; ++r) v[r] = (bf16_t)(o[dt][r] * inv);
    *(bf16x4_t*)&Cx[row + dt*16 + quad*4] = v;
  }
}

// ---------------------------------------------------------------------------
extern "C" void kernel_launch(void* const* d_in, const int* in_sizes, int n_in,
                              void* d_out, int out_size, void* d_ws, size_t ws_size,
                              hipStream_t stream) {
  (void)in_sizes; (void)n_in; (void)out_size;
  const float* query = (const float*)d_in[0];
  const float* key   = (const float*)d_in[1];
  const float* value = (const float*)d_in[2];
  const float* WqF   = (const float*)d_in[3];
  const float* WkF   = (const float*)d_in[4];
  const float* WvF   = (const float*)d_in[5];
  const float* WoF   = (const float*)d_in[6];

  const size_t AN = (size_t)MROWS*EMB;   // 8M elems
  const size_t WN = (size_t)EMB*EMB;     // 1M elems
  float* out = (float*)d_out;
  bf16_t* S5 = (bf16_t*)d_out;           // d_out first 16MB as bf16 scratch
  bf16_t* S6 = S5 + AN;                  // d_out second 16MB

  const float sscale = 0.125f * 1.44269504f;  // 1/sqrt(64)*log2(e) into Q

  const dim3 gqkv(EMB/128, MROWS/128, 3);
  const dim3 gqk (EMB/128, MROWS/128, 2);
  const dim3 gv  (EMB/128, MROWS/128, 1);
  const dim3 gg  (8, 128);               // 64x128 tiles: 1024 blocks
  const dim3 gattn(SS/128, HEADS, BB);

  if (ws_size >= (size_t)(4*AN + 4*WN) * sizeof(bf16_t)) {
    // ---- full-fusion path (ws >= 72MB): qb|kb|vb|S2|W in ws -------------
    bf16_t* qb  = (bf16_t*)d_ws;
    bf16_t* kb  = qb + AN;
    bf16_t* vb  = kb + AN;
    bf16_t* S2  = vb + AN;
    bf16_t* Wqb = S2 + AN;
    bf16_t* Wkb = Wqb + WN;
    bf16_t* Wvb = Wkb + WN;
    bf16_t* Wob = Wvb + WN;

    cast_multi<<<dim3(AN/2048, 1, 7), 256, 0, stream>>>(
        query, key, value, WqF, WkF, WvF, WoF,
        qb, kb, vb, Wqb, Wkb, Wvb, Wob, 3);
    gemm_qkv<<<gqkv, 256, 0, stream>>>(qb, kb, vb, Wqb, Wkb, Wvb,
                                       S2, S6, S5, sscale, 0);
    attn<<<gattn, 512, 0, stream>>>(S2, S6, S5, S2);
    gemm_out<<<gg, 256, 0, stream>>>(S2, Wob, out);
  } else {
    // ---- fallback path (ws >= 40MB proven): S1|S2|W in ws ---------------
    bf16_t* S1  = (bf16_t*)d_ws;
    bf16_t* S2  = S1 + AN;
    bf16_t* Wqb = S2 + AN;
    bf16_t* Wkb = Wqb + WN;
    bf16_t* Wvb = Wkb + WN;
    bf16_t* Wob = Wvb + WN;

    // z0: query->S1 (ws), z1: key->S5 (d_out), z2..5: weights
    cast_multi<<<dim3(AN/2048, 1, 6), 256, 0, stream>>>(
        query, key, WqF, WkF, WvF, WoF, WoF,
        S1, S5, Wqb, Wkb, Wvb, Wob, Wob, 2);
    gemm_qkv<<<gqk, 256, 0, stream>>>(S1, S5, S1, Wqb, Wkb, Wvb,
                                      S2, S6, S5, sscale, 0);   // Qp=S2, Kp=S6
    cast_f32_bf16<<<dim3(AN/2048), 256, 0, stream>>>(value, S1); // vb=S1 (qb dead)
    gemm_qkv<<<gv, 256, 0, stream>>>(S1, S1, S1, Wvb, Wvb, Wvb,
                                     S5, S5, S5, 1.0f, 2);      // Vt=S5 (kb dead)
    attn<<<gattn, 512, 0, stream>>>(S2, S6, S5, S2);            // Cx=S2
    gemm_out<<<gg, 256, 0, stream>>>(S2, Wob, out);
  }
}

// Round 13
// 312.348 us; speedup vs baseline: 1.2136x; 1.0374x over previous
//
#include <hip/hip_runtime.h>
#include <hip/hip_bf16.h>

#define EMB   1024
#define HEADS 16
#define HDIM  64
#define BB    4
#define SS    2048
#define MROWS (BB*SS)   // 8192

typedef __bf16 bf16_t;
typedef __bf16 bf16x4_t __attribute__((ext_vector_type(4)));
typedef __bf16 bf16x8   __attribute__((ext_vector_type(8)));
typedef float  f32x4    __attribute__((ext_vector_type(4)));

// async global->LDS, 16B/lane; LDS base wave-uniform, HW adds lane*16
__device__ __forceinline__ void glds16(const void* g, void* l) {
  __builtin_amdgcn_global_load_lds(
      (const __attribute__((address_space(1))) void*)g,
      (__attribute__((address_space(3))) void*)l, 16, 0, 0);
}

// ---------------------------------------------------------------------------
// Multi-tensor fp32->bf16 cast. z < nact: 8M-elem activations (4096 blocks);
// z >= nact: 1M-elem weights (first 512 blocks active).
// ---------------------------------------------------------------------------
__launch_bounds__(256)
__global__ void cast_multi(const float* s0, const float* s1, const float* s2,
                           const float* s3, const float* s4, const float* s5,
                           const float* s6,
                           bf16_t* d0, bf16_t* d1, bf16_t* d2, bf16_t* d3,
                           bf16_t* d4, bf16_t* d5, bf16_t* d6, int nact) {
  const int z = blockIdx.z;
  if (z >= nact && blockIdx.x >= 512) return;
  const float* ss[7] = {s0, s1, s2, s3, s4, s5, s6};
  bf16_t*      dd[7] = {d0, d1, d2, d3, d4, d5, d6};
  const float* s = ss[z];
  bf16_t*      d = dd[z];
  const int i = (blockIdx.x*256 + threadIdx.x) * 8;
  const f32x4 a = *(const f32x4*)&s[i];
  const f32x4 b = *(const f32x4*)&s[i+4];
  bf16x8 r;
  r[0]=(bf16_t)a[0]; r[1]=(bf16_t)a[1]; r[2]=(bf16_t)a[2]; r[3]=(bf16_t)a[3];
  r[4]=(bf16_t)b[0]; r[5]=(bf16_t)b[1]; r[6]=(bf16_t)b[2]; r[7]=(bf16_t)b[3];
  *(bf16x8*)&d[i] = r;
}

__launch_bounds__(256)
__global__ void cast_f32_bf16(const float* __restrict__ src, bf16_t* __restrict__ dst) {
  const int i = (blockIdx.x*256 + threadIdx.x) * 8;
  const f32x4 a = *(const f32x4*)&src[i];
  const f32x4 b = *(const f32x4*)&src[i+4];
  bf16x8 r;
  r[0]=(bf16_t)a[0]; r[1]=(bf16_t)a[1]; r[2]=(bf16_t)a[2]; r[3]=(bf16_t)a[3];
  r[4]=(bf16_t)b[0]; r[5]=(bf16_t)b[1]; r[6]=(bf16_t)b[2]; r[7]=(bf16_t)b[3];
  *(bf16x8*)&dst[i] = r;
}

// ---------------------------------------------------------------------------
// Shared GEMM core: acc[4][4] += A_tile @ W_tile^T over full K=EMB.
// 128x128 tile, BK=32, glds16 staging, 16 MFMA/K-step (m97 structure,
// single-buffered -- the R1-proven form).
// ---------------------------------------------------------------------------
__device__ __forceinline__ void gemm_core(const bf16_t* __restrict__ A,
                                          const bf16_t* __restrict__ W,
                                          bf16_t* As, bf16_t* Bs,
                                          f32x4 acc[4][4],
                                          int bm0, int bn0,
                                          int wave, int lane) {
  const int quad = lane >> 4, l16 = lane & 15;
  const int wm = wave >> 1, wn = wave & 1;
  for (int k0 = 0; k0 < EMB; k0 += 32) {
#pragma unroll
    for (int j = 0; j < 2; ++j) {
      const int i   = wave*2 + j;              // chunk 0..7 (512 bf16 = 1KB)
      const int row = i*16 + (lane >> 2);
      const int col = (lane & 3) * 8;
      glds16(A + (size_t)(bm0 + row)*EMB + k0 + col, &As[i*512]);
      glds16(W + (size_t)(bn0 + row)*EMB + k0 + col, &Bs[i*512]);
    }
    __syncthreads();

    bf16x8 a[4], b[4];
#pragma unroll
    for (int t = 0; t < 4; ++t) {
      a[t] = *(const bf16x8*)&As[(wm*64 + t*16 + l16)*32 + quad*8];
      b[t] = *(const bf16x8*)&Bs[(wn*64 + t*16 + l16)*32 + quad*8];
    }
#pragma unroll
    for (int mt = 0; mt < 4; ++mt)
#pragma unroll
      for (int nt = 0; nt < 4; ++nt)
        acc[mt][nt] = __builtin_amdgcn_mfma_f32_16x16x32_bf16(a[mt], b[nt], acc[mt][nt], 0, 0, 0);
    __syncthreads();
  }
}

// ---------------------------------------------------------------------------
// Fused projection GEMM with XCD-aware swizzle.  Flat block id fid is
// round-robined over 8 XCDs by HW; we remap so each (z,bm) A-panel is owned
// by exactly one XCD (read once from HBM) with bn iterating time-locally,
// and W(z) (2MB) staying hot in that XCD's 4MB L2.
//   z (+zbase): 0 = Q (row-major, sscale), 1 = K (row-major), 2 = V (packed).
// ---------------------------------------------------------------------------
__launch_bounds__(256)
__global__ void gemm_qkv(const bf16_t* A0, const bf16_t* A1, const bf16_t* A2,
                         const bf16_t* W0, const bf16_t* W1, const bf16_t* W2,
                         bf16_t* C0, bf16_t* C1, bf16_t* C2,
                         float sscale, int zbase) {
  __shared__ __align__(16) bf16_t As[128*32];
  __shared__ __align__(16) bf16_t Bs[128*32];
  const int tid  = threadIdx.x;
  const int wave = tid >> 6, lane = tid & 63;
  const int quad = lane >> 4, l16 = lane & 15;
  const int wm = wave >> 1, wn = wave & 1;

  // XCD swizzle: fid -> (z, bm, bn)
  const int fid = blockIdx.x + 8*(blockIdx.y + 64*blockIdx.z);
  const int xcd = fid & 7, s = fid >> 3;
  const int bn0 = (s & 7) * 128;
  const int p   = xcd + 8*(s >> 3);            // (z,bm) pair, unique per XCD
  const int z   = (p >> 6) + zbase;
  const int bm0 = (p & 63) * 128;

  const bf16_t* A = (z == 0) ? A0 : (z == 1) ? A1 : A2;
  const bf16_t* W = (z == 0) ? W0 : (z == 1) ? W1 : W2;
  bf16_t*       C = (z == 0) ? C0 : (z == 1) ? C1 : C2;
  const float oscale = (z == 0) ? sscale : 1.0f;

  f32x4 acc[4][4] = {};
  gemm_core(A, W, As, Bs, acc, bm0, bn0, wave, lane);

  if (z == 2) {
    // packed-V^T epilogue: acc[mt][nt][r] = V[s=bm0+wm*64+mt*16+quad*4+r][d]
    // chunk(ks,nt) = {acc[2ks][nt][0..3], acc[2ks+1][nt][0..3]}
    const int bb = bm0 >> 11;                    // batch (2048 rows each)
    const int T  = ((bm0 & 2047) >> 6) + wm;     // 64-key tile within batch
    const int h  = (bn0 >> 6) + wn;              // head (64 cols each)
    bf16_t* base = C + ((size_t)(bb*HEADS + h)*32 + T)*4096;
#pragma unroll
    for (int ks = 0; ks < 2; ++ks)
#pragma unroll
      for (int nt = 0; nt < 4; ++nt) {
        bf16x8 v;
#pragma unroll
        for (int r = 0; r < 4; ++r) {
          v[r]     = (bf16_t)acc[2*ks][nt][r];
          v[4 + r] = (bf16_t)acc[2*ks + 1][nt][r];
        }
        *(bf16x8*)&base[((nt*2 + ks)*64 + quad*16 + l16)*8] = v;
      }
  } else {
    // row-major epilogue: C/D layout col=l16, row=quad*4+reg
#pragma unroll
    for (int mt = 0; mt < 4; ++mt) {
      const int row = bm0 + wm*64 + mt*16 + quad*4;
#pragma unroll
      for (int nt = 0; nt < 4; ++nt) {
        const int col = bn0 + wn*64 + nt*16 + l16;
#pragma unroll
        for (int r = 0; r < 4; ++r)
          C[(size_t)(row + r)*EMB + col] = (bf16_t)(acc[mt][nt][r] * oscale);
      }
    }
  }
}

// ---------------------------------------------------------------------------
// Output GEMM: fp32 C, row-major.  64x128 tile, single-buffered (R10-proven:
// -9us vs 128x128).  1024 blocks -> 4 blocks/CU, 16 waves/CU.  acc[2][4],
// LDS 12KB.  XCD swizzle: each XCD owns 16 consecutive 64-row bm-panels.
// ---------------------------------------------------------------------------
__launch_bounds__(256)
__global__ void gemm_out(const bf16_t* __restrict__ A, const bf16_t* __restrict__ W,
                         float* __restrict__ C) {
  __shared__ __align__(16) bf16_t As[64*32];     // 4KB
  __shared__ __align__(16) bf16_t Bs[128*32];    // 8KB
  const int tid  = threadIdx.x;
  const int wave = tid >> 6, lane = tid & 63;
  const int quad = lane >> 4, l16 = lane & 15;
  const int wm = wave >> 1, wn = wave & 1;       // wave: 32 rows x 64 cols

  // grid (8,128): fid -> xcd 0..7, s 0..127
  const int fid = blockIdx.x + 8*blockIdx.y;
  const int xcd = fid & 7, s = fid >> 3;
  const int bn0 = (s & 7) * 128;
  const int bm0 = (xcd*16 + (s >> 3)) * 64;      // 16 bm-panels per XCD

  f32x4 acc[2][4] = {};

  for (int k0 = 0; k0 < EMB; k0 += 32) {
    {
      const int i   = wave;                      // A chunk 0..3
      const int row = i*16 + (lane >> 2);
      const int col = (lane & 3) * 8;
      glds16(A + (size_t)(bm0 + row)*EMB + k0 + col, &As[i*512]);
    }
#pragma unroll
    for (int j = 0; j < 2; ++j) {
      const int i   = wave*2 + j;                // B chunk 0..7
      const int row = i*16 + (lane >> 2);
      const int col = (lane & 3) * 8;
      glds16(W + (size_t)(bn0 + row)*EMB + k0 + col, &Bs[i*512]);
    }
    __syncthreads();

    bf16x8 a[2], b[4];
#pragma unroll
    for (int t2 = 0; t2 < 2; ++t2)
      a[t2] = *(const bf16x8*)&As[(wm*32 + t2*16 + l16)*32 + quad*8];
#pragma unroll
    for (int t2 = 0; t2 < 4; ++t2)
      b[t2] = *(const bf16x8*)&Bs[(wn*64 + t2*16 + l16)*32 + quad*8];
#pragma unroll
    for (int mt = 0; mt < 2; ++mt)
#pragma unroll
      for (int nt = 0; nt < 4; ++nt)
        acc[mt][nt] = __builtin_amdgcn_mfma_f32_16x16x32_bf16(a[mt], b[nt], acc[mt][nt], 0, 0, 0);
    __syncthreads();
  }

#pragma unroll
  for (int mt = 0; mt < 2; ++mt) {
    const int row = bm0 + wm*32 + mt*16 + quad*4;
#pragma unroll
    for (int nt = 0; nt < 4; ++nt) {
      const int col = bn0 + wn*64 + nt*16 + l16;
#pragma unroll
      for (int r = 0; r < 4; ++r)
        C[(size_t)(row + r)*EMB + col] = acc[mt][nt][r];
    }
  }
}

// ---------------------------------------------------------------------------
// Flash attention, Q-tile 128, 8 waves x 16 q-rows (512 threads), K-tile 64.
// S^T = MFMA(A=K, B=Q) gives the P^T B-operand layout directly; packed V^T
// from the V-GEMM epilogue is the A-operand of O^T = V^T P^T.  No-max
// softmax (scale folded into Q), raw v_exp_f32, deferred l-reduction.
//
// R13: R12's QK(t+1)||PV(t) pipeline with SINGLE barrier per tile via
// asymmetric buffering Ks[2] / Vs[3] (40KB).  R12 needed bar2 only because
// stage(t+2) reused the V buffer PV(t) just read; a 3rd V buffer removes
// that hazard:
//   iter t: bar (drains stage t+1; all iter t-1 reads done)
//           -> stage(t+2 -> Ks[t&1], Vs[(t+2)%3])   [disjoint from reads]
//           -> setprio(1) QK(t+1, Ks[(t+1)&1]) + PV(t, Vs[t%3]) setprio(0)
//           -> SM(t+1) -> pb.
// Hazard audit: Ks[t&1] held K(t), last read by QK(t) in iter t-1 (pre-bar);
// Vs[(t+2)%3] held V(t-1), read by PV(t-1) in iter t-1 (pre-bar).  Each
// barrier drains exactly one stage issued a full tile earlier.  Grid is
// 4 blocks/CU (1024 blocks) so 40KB LDS does not change occupancy.
// K staged in MFMA A-frag order via per-lane global src (conflict-free);
// packed V^T is an identity copy.  XCD swizzle: 16 q-blocks of one (b,h)
// per XCD.  Qp and Cx alias (disjoint per-block slices).
// ---------------------------------------------------------------------------
__launch_bounds__(512, 8)
__global__ void attn(const bf16_t* Qp, const bf16_t* __restrict__ Kp,
                     const bf16_t* __restrict__ Vt, bf16_t* Cx) {
  __shared__ __align__(16) bf16_t Ks[2][4096];  // 16KB
  __shared__ __align__(16) bf16_t Vs[3][4096];  // 24KB

  const int tid  = threadIdx.x;
  const int wave = tid >> 6, lane = tid & 63;
  const int quad = lane >> 4, l16 = lane & 15;

  // XCD swizzle: fid -> (b, h, q-block); gridDim = (16, 16, 4)
  const int fid  = blockIdx.x + 16*(blockIdx.y + 16*blockIdx.z);
  const int xcd  = fid & 7, s = fid >> 3;
  const int q0   = (s & 15) * 128;
  const int pair = xcd*8 + (s >> 4);    // 0..63, unique per XCD
  const int h    = pair & 15;
  const int b    = pair >> 4;

  // Q fragments (B-operand of S^T): lane l16 = qrow, k = d = quad*8+j (+32ks)
  bf16x8 qf[2];
  {
    const size_t qr = (size_t)(b*SS + q0 + wave*16 + l16)*EMB + h*HDIM;
    qf[0] = *(const bf16x8*)&Qp[qr + quad*8];
    qf[1] = *(const bf16x8*)&Qp[qr + 32 + quad*8];
  }

  const bf16_t* Kb = Kp + (size_t)b*SS*EMB + h*HDIM;
  const bf16_t* Vb = Vt + ((size_t)(b*HEADS + h)*32)*4096;

  f32x4 o[4] = {};             // O^T: lane l16 = qrow, row = d = quad*4+r
  f32x4 lsv = {};              // packed denominator accumulator
  bf16x8 pb[2];                // packed P^T B-fragments (pipeline register)

  // stage K/V tile ti: 1 K-chunk + 1 V-chunk per wave, explicit buffers.
  auto stage = [&](int ti, int kbuf, int vbuf) {
    const int t0 = ti * 64;
    const int i  = wave;                 // chunk 0..7
    glds16(Kb + (size_t)(t0 + (i&3)*16 + l16)*EMB + (i>>2)*32 + quad*8,
           &Ks[kbuf][i*512]);
    glds16(Vb + (size_t)ti*4096 + i*512 + lane*8, &Vs[vbuf][i*512]);
  };

  // S^T = K Q^T : A = K-frag (lane l16 = key), B = Q-frag  (8 MFMA)
  auto QK = [&](int bf, f32x4 (&st)[4]) {
#pragma unroll
    for (int cb = 0; cb < 4; ++cb) {
      const bf16x8 kf0 = *(const bf16x8*)&Ks[bf][cb*512 + lane*8];
      const bf16x8 kf1 = *(const bf16x8*)&Ks[bf][2048 + cb*512 + lane*8];
      st[cb] = __builtin_amdgcn_mfma_f32_16x16x32_bf16(kf0, qf[0], st[cb], 0, 0, 0);
      st[cb] = __builtin_amdgcn_mfma_f32_16x16x32_bf16(kf1, qf[1], st[cb], 0, 0, 0);
    }
  };

  // softmax (no-max): p = exp2(s); pack P^T B-fragments directly from regs
  auto SM = [&](f32x4 (&st)[4]) {
#pragma unroll
    for (int kb = 0; kb < 4; ++kb) {
#pragma unroll
      for (int r = 0; r < 4; ++r)
        st[kb][r] = __builtin_amdgcn_exp2f(st[kb][r]);
      lsv += st[kb];           // packed v_pk_add_f32
    }
#pragma unroll
    for (int ks = 0; ks < 2; ++ks)
#pragma unroll
      for (int r = 0; r < 4; ++r) {
        pb[ks][r]     = (bf16_t)st[2*ks][r];
        pb[ks][4 + r] = (bf16_t)st[2*ks + 1][r];
      }
  };

  // O^T += V^T P^T : A = packed V^T chunk, B = pb  (8 MFMA)
  auto PV = [&](int bf) {
#pragma unroll
    for (int ks = 0; ks < 2; ++ks)
#pragma unroll
      for (int dt = 0; dt < 4; ++dt) {
        const bf16x8 vf = *(const bf16x8*)&Vs[bf][((dt*2 + ks)*64 + lane)*8];
        o[dt] = __builtin_amdgcn_mfma_f32_16x16x32_bf16(vf, pb[ks], o[dt], 0, 0, 0);
      }
  };

  // ---- prologue: tile 0 computed to P; tile 1 staged in flight -----------
  stage(0, 0, 0);
  __syncthreads();             // drains stage(0)
  stage(1, 1, 1);
  {
    f32x4 st[4] = {};
    QK(0, st);
    SM(st);                    // pb = P(0)
  }

  // ---- main pipeline: iter t finishes tile t, preps tile t+1 -------------
  const int NT = SS / 64;      // 32 tiles
  int vr = 0;                  // PV read buffer: t%3
  int vw = 2;                  // stage write buffer: (t+2)%3
  for (int t = 0; t < NT - 1; ++t) {
    __syncthreads();           // drains stage(t+1); all iter t-1 reads done
    if (t + 2 < NT) stage(t + 2, t & 1, vw);
    __builtin_amdgcn_s_setprio(1);
    f32x4 stn[4] = {};
    QK((t + 1) & 1, stn);      // QK(t+1)  -- independent of PV(t)
    PV(vr);                    // PV(t)    -- consumes pb(t), Vs[t%3]
    __builtin_amdgcn_s_setprio(0);
    SM(stn);                   // pb = P(t+1); stage drains at next barrier
    vr = (vr == 2) ? 0 : vr + 1;
    vw = (vw == 2) ? 0 : vw + 1;
  }

  // ---- epilogue: PV(NT-1) from Vs[(NT-1)%3] ------------------------------
  PV(vr);

  // l-reduce across quads (lanes sharing l16) + write O^T as [row][h*64+d]
  float l = lsv[0] + lsv[1] + lsv[2] + lsv[3];
  l += __shfl_xor(l, 16, 64);
  l += __shfl_xor(l, 32, 64);
  const float inv = 1.0f / l;
  const size_t row = (size_t)(b*SS + q0 + wave*16 + l16)*EMB + h*HDIM;
#pragma unroll
  for (int dt = 0; dt < 4; ++dt) {
    bf16x4_t v;
#pragma unroll
    for (int r = 0; r < 4; ++r) v[r] = (bf16_t)(o[dt][r] * inv);
    *(bf16x4_t*)&Cx[row + dt*16 + quad*4] = v;
  }
}

// ---------------------------------------------------------------------------
extern "C" void kernel_launch(void* const* d_in, const int* in_sizes, int n_in,
                              void* d_out, int out_size, void* d_ws, size_t ws_size,
                              hipStream_t stream) {
  (void)in_sizes; (void)n_in; (void)out_size;
  const float* query = (const float*)d_in[0];
  const float* key   = (const float*)d_in[1];
  const float* value = (const float*)d_in[2];
  const float* WqF   = (const float*)d_in[3];
  const float* WkF   = (const float*)d_in[4];
  const float* WvF   = (const float*)d_in[5];
  const float* WoF   = (const float*)d_in[6];

  const size_t AN = (size_t)MROWS*EMB;   // 8M elems
  const size_t WN = (size_t)EMB*EMB;     // 1M elems
  float* out = (float*)d_out;
  bf16_t* S5 = (bf16_t*)d_out;           // d_out first 16MB as bf16 scratch
  bf16_t* S6 = S5 + AN;                  // d_out second 16MB

  const float sscale = 0.125f * 1.44269504f;  // 1/sqrt(64)*log2(e) into Q

  const dim3 gqkv(EMB/128, MROWS/128, 3);
  const dim3 gqk (EMB/128, MROWS/128, 2);
  const dim3 gv  (EMB/128, MROWS/128, 1);
  const dim3 gg  (8, 128);               // 64x128 tiles: 1024 blocks
  const dim3 gattn(SS/128, HEADS, BB);

  if (ws_size >= (size_t)(4*AN + 4*WN) * sizeof(bf16_t)) {
    // ---- full-fusion path (ws >= 72MB): qb|kb|vb|S2|W in ws -------------
    bf16_t* qb  = (bf16_t*)d_ws;
    bf16_t* kb  = qb + AN;
    bf16_t* vb  = kb + AN;
    bf16_t* S2  = vb + AN;
    bf16_t* Wqb = S2 + AN;
    bf16_t* Wkb = Wqb + WN;
    bf16_t* Wvb = Wkb + WN;
    bf16_t* Wob = Wvb + WN;

    cast_multi<<<dim3(AN/2048, 1, 7), 256, 0, stream>>>(
        query, key, value, WqF, WkF, WvF, WoF,
        qb, kb, vb, Wqb, Wkb, Wvb, Wob, 3);
    gemm_qkv<<<gqkv, 256, 0, stream>>>(qb, kb, vb, Wqb, Wkb, Wvb,
                                       S2, S6, S5, sscale, 0);
    attn<<<gattn, 512, 0, stream>>>(S2, S6, S5, S2);
    gemm_out<<<gg, 256, 0, stream>>>(S2, Wob, out);
  } else {
    // ---- fallback path (ws >= 40MB proven): S1|S2|W in ws ---------------
    bf16_t* S1  = (bf16_t*)d_ws;
    bf16_t* S2  = S1 + AN;
    bf16_t* Wqb = S2 + AN;
    bf16_t* Wkb = Wqb + WN;
    bf16_t* Wvb = Wkb + WN;
    bf16_t* Wob = Wvb + WN;

    // z0: query->S1 (ws), z1: key->S5 (d_out), z2..5: weights
    cast_multi<<<dim3(AN/2048, 1, 6), 256, 0, stream>>>(
        query, key, WqF, WkF, WvF, WoF, WoF,
        S1, S5, Wqb, Wkb, Wvb, Wob, Wob, 2);
    gemm_qkv<<<gqk, 256, 0, stream>>>(S1, S5, S1, Wqb, Wkb, Wvb,
                                      S2, S6, S5, sscale, 0);   // Qp=S2, Kp=S6
    cast_f32_bf16<<<dim3(AN/2048), 256, 0, stream>>>(value, S1); // vb=S1 (qb dead)
    gemm_qkv<<<gv, 256, 0, stream>>>(S1, S1, S1, Wvb, Wvb, Wvb,
                                     S5, S5, S5, 1.0f, 2);      // Vt=S5 (kb dead)
    attn<<<gattn, 512, 0, stream>>>(S2, S6, S5, S2);            // Cx=S2
    gemm_out<<<gg, 256, 0, stream>>>(S2, Wob, out);
  }
}